// Round 1
// baseline (4025.120 us; speedup 1.0000x reference)
//
#include <hip/hip_runtime.h>
#include <hip/hip_fp16.h>

// SimpleHybridModel: conv1d(k=3,SAME,relu) -> SimpleRNN(16,tanh,last) -> dense(8,relu) -> dense(1)
// B=262144, L=20, F=7, C=H=16, D1=8. All f32 in/out; x staged in LDS as f16.

#define BLK 128           // threads per block == batch elements per block
#define LSEQ 20
#define NF 7
#define LF (LSEQ*NF)      // 140 floats per element

// weight LDS layout offsets (floats)
#define W_CONV   0        // 336 = 3*7*16  [k][f][co]
#define W_CONVB  336      // 16
#define W_RNNW   352      // 256 [c][h]
#define W_RNNU   608      // 256 [j][h]
#define W_RNNB   864      // 16
#define W_D1W    880      // 128 [h][d]
#define W_D1B    1008     // 8
#define W_OUTW   1016     // 8
#define W_OUTB   1024     // 1

__global__ __launch_bounds__(BLK, 2) void hybrid_fwd(
    const float* __restrict__ x,
    const float* __restrict__ conv_w, const float* __restrict__ conv_b,
    const float* __restrict__ rnn_w,  const float* __restrict__ rnn_u,
    const float* __restrict__ rnn_b,
    const float* __restrict__ d1_w,   const float* __restrict__ d1_b,
    const float* __restrict__ out_w,  const float* __restrict__ out_b,
    float* __restrict__ out)
{
    __shared__ __half xs[BLK * LF];   // 35840 B, linear: xs[i] = (half)x_tile_flat[i]
    __shared__ float  w[1032];        // 4128 B

    const int tid = threadIdx.x;
    const long blockBase = (long)blockIdx.x * (BLK * LF);

    // ---- stage x tile: contiguous float4 loads -> half2 -> LDS (linear) ----
    const float4* xsrc = (const float4*)(x + blockBase);
    #pragma unroll
    for (int i = 0; i < LF / 4; ++i) {          // 35 iters
        int idx = tid + i * BLK;
        float4 v = xsrc[idx];
        __half2* dst = (__half2*)(xs + idx * 4);
        dst[0] = __floats2half2_rn(v.x, v.y);
        dst[1] = __floats2half2_rn(v.z, v.w);
    }
    // ---- stage weights ----
    for (int i = tid; i < 336; i += BLK) w[W_CONV  + i] = conv_w[i];
    for (int i = tid; i < 16;  i += BLK) w[W_CONVB + i] = conv_b[i];
    for (int i = tid; i < 256; i += BLK) w[W_RNNW  + i] = rnn_w[i];
    for (int i = tid; i < 256; i += BLK) w[W_RNNU  + i] = rnn_u[i];
    for (int i = tid; i < 16;  i += BLK) w[W_RNNB  + i] = rnn_b[i];
    for (int i = tid; i < 128; i += BLK) w[W_D1W   + i] = d1_w[i];
    for (int i = tid; i < 8;   i += BLK) { w[W_D1B + i] = d1_b[i]; w[W_OUTW + i] = out_w[i]; }
    if (tid == 0) w[W_OUTB] = out_b[0];
    __syncthreads();

    const __half* myx = xs + tid * LF;

    float h[16];
    #pragma unroll
    for (int i = 0; i < 16; ++i) h[i] = 0.f;

    for (int l = 0; l < LSEQ; ++l) {
        // ---- conv1d (k=3, SAME) + bias ----
        float c[16];
        #pragma unroll
        for (int co = 0; co < 16; ++co) c[co] = w[W_CONVB + co];
        #pragma unroll
        for (int kk = 0; kk < 3; ++kk) {
            int ll = l + kk - 1;
            float m = (ll >= 0 && ll < LSEQ) ? 1.f : 0.f;   // branchless SAME padding
            int lc = min(max(ll, 0), LSEQ - 1);
            #pragma unroll
            for (int f = 0; f < NF; ++f) {
                float xv = m * __half2float(myx[lc * NF + f]);
                #pragma unroll
                for (int co = 0; co < 16; ++co)
                    c[co] = fmaf(xv, w[W_CONV + (kk * NF + f) * 16 + co], c[co]);
            }
        }
        // ---- s = relu(c) @ rnn_w + rnn_b + h @ rnn_u ----
        float s[16];
        #pragma unroll
        for (int hh = 0; hh < 16; ++hh) s[hh] = w[W_RNNB + hh];
        #pragma unroll
        for (int cc = 0; cc < 16; ++cc) {
            float r = fmaxf(c[cc], 0.f);
            #pragma unroll
            for (int hh = 0; hh < 16; ++hh)
                s[hh] = fmaf(r, w[W_RNNW + cc * 16 + hh], s[hh]);
        }
        #pragma unroll
        for (int jj = 0; jj < 16; ++jj) {
            float hv = h[jj];
            #pragma unroll
            for (int hh = 0; hh < 16; ++hh)
                s[hh] = fmaf(hv, w[W_RNNU + jj * 16 + hh], s[hh]);
        }
        // ---- h = tanh(s) via fast exp ----
        #pragma unroll
        for (int hh = 0; hh < 16; ++hh) {
            float e = __expf(2.f * s[hh]);
            h[hh] = 1.f - 2.f / (1.f + e);
        }
    }

    // ---- head: relu(h @ d1_w + d1_b) @ out_w + out_b ----
    float acc = w[W_OUTB];
    #pragma unroll
    for (int d = 0; d < 8; ++d) {
        float z = w[W_D1B + d];
        #pragma unroll
        for (int hh = 0; hh < 16; ++hh)
            z = fmaf(h[hh], w[W_D1W + hh * 8 + d], z);
        z = fmaxf(z, 0.f);
        acc = fmaf(z, w[W_OUTW + d], acc);
    }
    out[(long)blockIdx.x * BLK + tid] = acc;
}

extern "C" void kernel_launch(void* const* d_in, const int* in_sizes, int n_in,
                              void* d_out, int out_size, void* d_ws, size_t ws_size,
                              hipStream_t stream) {
    const float* x      = (const float*)d_in[0];
    const float* conv_w = (const float*)d_in[1];
    const float* conv_b = (const float*)d_in[2];
    const float* rnn_w  = (const float*)d_in[3];
    const float* rnn_u  = (const float*)d_in[4];
    const float* rnn_b  = (const float*)d_in[5];
    const float* d1_w   = (const float*)d_in[6];
    const float* d1_b   = (const float*)d_in[7];
    const float* out_w  = (const float*)d_in[8];
    const float* out_b  = (const float*)d_in[9];
    float* out = (float*)d_out;

    const int B = out_size;                 // 262144
    const int grid = B / BLK;               // 2048
    hybrid_fwd<<<grid, BLK, 0, stream>>>(x, conv_w, conv_b, rnn_w, rnn_u, rnn_b,
                                         d1_w, d1_b, out_w, out_b, out);
}